// Round 6
// baseline (306.965 us; speedup 1.0000x reference)
//
#include <hip/hip_runtime.h>
#include <math.h>

// Problem constants (fixed by setup_inputs): N=4, K=11, H=W=256.
#define NB    4
#define KF    11
#define KK    121
#define HH    256
#define WW    256
#define HW    (HH * WW)
#define HW2   (HW / 2)
#define PADK  5
#define RPB   2                    // rows per block (128 threads per row)
#define TROWS (RPB + KF - 1)       // 12 tile rows
#define TW2   268                  // padded tile width, 8B-aligned spans
#define INVD  (1.0f / 255.0f)
#define HALF  (NB * HH / RPB)      // 512 blocks per direction

// Kernel X: both first passes in parallel.
//   bid < HALF : m1A = flow(grid, FA)
//   bid >= HALF: m1B = flow(grid, FB)
// 1024 blocks x 256 thr = 16 waves/CU.
__global__ __launch_bounds__(256) void passX_kernel(const float* __restrict__ FA,
                                                    const float* __restrict__ FB,
                                                    float* __restrict__ m1A,
                                                    float* __restrict__ m1B) {
    const int bid = blockIdx.x;
    const bool dirA = (bid < HALF);
    const int b = dirA ? bid : bid - HALF;
    const float* F  = dirA ? FA : FB;
    float*       m1 = dirA ? m1A : m1B;

    const int t   = threadIdx.x;
    const int n   = b / (HH / RPB);
    const int h0  = (b % (HH / RPB)) * RPB;
    const int sub = t >> 7;
    const int j   = t & 127;
    const int h   = h0 + sub;
    const int w0  = j * 2;

    float mk0[KF], mk1[KF];
#pragma unroll
    for (int kx = 0; kx < KF; ++kx) {
        int c0 = w0 + kx - PADK;
        mk0[kx] = (c0 >= 0 && c0 < WW) ? 1.0f : 0.0f;
        mk1[kx] = (c0 + 1 >= 0 && c0 + 1 < WW) ? 1.0f : 0.0f;
    }
    const float b0 = (float)(w0 - PADK) * INVD;

    const float2* fp = (const float2*)(F + (size_t)n * KK * HW + (size_t)h * WW + w0);

    float ax0 = 0, ax1 = 0, ay0 = 0, ay1 = 0;
    for (int ky = 0; ky < KF; ++ky) {
        int rr = h + ky - PADK;
        if (rr < 0 || rr >= HH) continue;        // wave-uniform
        float yv = (float)rr * INVD;
        const float2* fr = fp + (size_t)(ky * KF) * HW2;

        float2 fq[KF];                            // 11 loads in flight
#pragma unroll
        for (int kx = 0; kx < KF; ++kx) fq[kx] = fr[(size_t)kx * HW2];

        float s0 = 0, s1 = 0;
#pragma unroll
        for (int kx = 0; kx < KF; ++kx) {
            float2 f = fq[kx];
            float xk = b0 + (float)kx * INVD;
            float u0 = f.x * mk0[kx], u1 = f.y * mk1[kx];
            ax0 = fmaf(u0, xk, ax0);
            ax1 = fmaf(u1, xk + INVD, ax1);
            s0 += u0; s1 += u1;
        }
        ay0 = fmaf(yv, s0, ay0);
        ay1 = fmaf(yv, s1, ay1);
    }
    *(float2*)(m1 + (size_t)n * 2 * HW + (size_t)h * WW + w0)      = make_float2(ax0, ax1);
    *(float2*)(m1 + (size_t)n * 2 * HW + HW + (size_t)h * WW + w0) = make_float2(ay0, ay1);
}

// Kernel Y: both second passes in parallel + loss partials.
//   bid < HALF : m2A = flow(m1A, FB) -> partial[bid]
//   bid >= HALF: m2B = flow(m1B, FA) -> partial[bid]
__global__ __launch_bounds__(256) void passY_kernel(const float* __restrict__ FA,
                                                    const float* __restrict__ FB,
                                                    const float* __restrict__ m1A,
                                                    const float* __restrict__ m1B,
                                                    float* __restrict__ partial) {
    __shared__ __align__(16) float tile[2 * TROWS * TW2];   // 25.7 KB
    __shared__ float wsum[4];

    const int bid = blockIdx.x;
    const bool dirA = (bid < HALF);
    const int b = dirA ? bid : bid - HALF;
    const float* F    = dirA ? FB : FA;     // second hop uses the OTHER filter
    const float* m1in = dirA ? m1A : m1B;

    const int t   = threadIdx.x;
    const int n   = b / (HH / RPB);
    const int h0  = (b % (HH / RPB)) * RPB;
    const int sub = t >> 7;
    const int j   = t & 127;
    const int h   = h0 + sub;
    const int w0  = j * 2;

    // Stage 12-row x 268-col x 2-ch m1in neighborhood into LDS (L2-hot).
    const float* mbase = m1in + (size_t)n * 2 * HW;
    for (int i = t; i < 2 * TROWS * TW2; i += 256) {
        int ch  = i / (TROWS * TW2);
        int rem = i - ch * (TROWS * TW2);
        int r   = rem / TW2;
        int c   = rem - r * TW2;
        int rr  = h0 + r - PADK;
        int cc  = c - PADK;
        float v = 0.0f;
        if (rr >= 0 && rr < HH && cc >= 0 && cc < WW)
            v = mbase[(size_t)ch * HW + rr * WW + cc];
        tile[i] = v;
    }
    __syncthreads();

    const float2* fp = (const float2*)(F + (size_t)n * KK * HW + (size_t)h * WW + w0);

    float a2x0 = 0, a2x1 = 0, a2y0 = 0, a2y1 = 0;
    for (int ky = 0; ky < KF; ++ky) {
        int rr = h + ky - PADK;
        if (rr < 0 || rr >= HH) continue;        // wave-uniform; tile rows zero anyway
        const float2* fr = fp + (size_t)(ky * KF) * HW2;

        float2 fq[KF];                            // 11 loads in flight
#pragma unroll
        for (int kx = 0; kx < KF; ++kx) fq[kx] = fr[(size_t)kx * HW2];

        // Register-cache this ky's tile span: cols w0..w0+11, both channels.
        const float* tx = tile + (sub + ky) * TW2 + w0;   // 8B-aligned
        const float* ty = tx + TROWS * TW2;
        float cx[12], cy[12];
#pragma unroll
        for (int q = 0; q < 6; ++q) {
            float2 vx = *(const float2*)(tx + 2 * q);
            float2 vy = *(const float2*)(ty + 2 * q);
            cx[2 * q] = vx.x; cx[2 * q + 1] = vx.y;
            cy[2 * q] = vy.x; cy[2 * q + 1] = vy.y;
        }

#pragma unroll
        for (int kx = 0; kx < KF; ++kx) {
            float2 f = fq[kx];
            a2x0 = fmaf(f.x, cx[kx], a2x0);
            a2x1 = fmaf(f.y, cx[kx + 1], a2x1);
            a2y0 = fmaf(f.x, cy[kx], a2y0);
            a2y1 = fmaf(f.y, cy[kx + 1], a2y1);
        }
    }

    float gx = (float)w0 * INVD, gy = (float)h * INVD;
    float dx0 = gx - a2x0,        dy0 = gy - a2y0;
    float dx1 = gx + INVD - a2x1, dy1 = gy - a2y1;
    float d = sqrtf(dx0 * dx0 + dy0 * dy0) + sqrtf(dx1 * dx1 + dy1 * dy1);

#pragma unroll
    for (int off = 32; off > 0; off >>= 1) d += __shfl_down(d, off, 64);
    if ((t & 63) == 0) wsum[t >> 6] = d;
    __syncthreads();
    if (t == 0) partial[bid] = wsum[0] + wsum[1] + wsum[2] + wsum[3];
}

__global__ __launch_bounds__(256) void finalize_kernel(const float* __restrict__ partial,
                                                       float* __restrict__ out) {
    __shared__ float wsum[4];
    int t = threadIdx.x;
    float s = partial[t] + partial[t + 256] + partial[t + 512] + partial[t + 768];
#pragma unroll
    for (int off = 32; off > 0; off >>= 1) s += __shfl_down(s, off, 64);
    if ((t & 63) == 0) wsum[t >> 6] = s;
    __syncthreads();
    if (t == 0)
        out[0] = (wsum[0] + wsum[1] + wsum[2] + wsum[3]) * (1.0f / ((float)HW * (float)NB));
}

extern "C" void kernel_launch(void* const* d_in, const int* in_sizes, int n_in,
                              void* d_out, int out_size, void* d_ws, size_t ws_size,
                              hipStream_t stream) {
    const float* FA = (const float*)d_in[0];  // FF_AtoB
    const float* FB = (const float*)d_in[1];  // FF_BtoA
    float* out = (float*)d_out;

    float* m1A = (float*)d_ws;                       // [N,2,H,W] = 2 MB
    float* m1B = m1A + (size_t)NB * 2 * HW;          // [N,2,H,W] = 2 MB
    float* partial = m1B + (size_t)NB * 2 * HW;      // 1024 floats, all rewritten

    // X: m1A = flow(grid,FA)  ||  m1B = flow(grid,FB)   (254 MB cold, 16 waves/CU)
    passX_kernel<<<dim3(2 * HALF), dim3(256), 0, stream>>>(FA, FB, m1A, m1B);
    // Y: m2A = flow(m1A,FB)   ||  m2B = flow(m1B,FA)    (254 MB, L3-warm)
    passY_kernel<<<dim3(2 * HALF), dim3(256), 0, stream>>>(FA, FB, m1A, m1B, partial);
    finalize_kernel<<<1, dim3(256), 0, stream>>>(partial, out);
}